// Round 6
// baseline (83.805 us; speedup 1.0000x reference)
//
#include <hip/hip_runtime.h>

#define HH 256
#define WW 256
#define TT 32
#define PLANE (HH * WW)

struct alignas(16) F4 { float x, y, z, w; };
__device__ inline F4 operator+(F4 a, F4 b) { return {a.x+b.x, a.y+b.y, a.z+b.z, a.w+b.w}; }
__device__ inline F4 operator-(F4 a, F4 b) { return {a.x-b.x, a.y-b.y, a.z-b.z, a.w-b.w}; }
__device__ inline F4 operator*(F4 a, F4 b) { return {a.x*b.x, a.y*b.y, a.z*b.z, a.w*b.w}; }
__device__ inline F4 operator*(F4 a, float s) { return {a.x*s, a.y*s, a.z*s, a.w*s}; }
__device__ inline F4 operator*(float s, F4 a) { return {a.x*s, a.y*s, a.z*s, a.w*s}; }

__global__ __launch_bounds__(256) void pil_main(const float* __restrict__ p,
                                                const float* __restrict__ Kf,
                                                double* __restrict__ ws) {
  __shared__ double redN[4];
  __shared__ int redD[4];

  const int rg = blockIdx.x;      // row group 0..63 (4 rows per block)
  const int b = blockIdx.y;       // 0..15

  const int tid = threadIdx.x;
  const int wid = tid >> 6;       // wave index = row within group
  const int lane = tid & 63;
  const int i = (rg << 2) + wid;  // global row (wave-uniform)
  const int j0 = lane << 2;       // first of 4 cols

  const float i2hx = 0.02f;       // 1/(2*25)
  const float i2hy = 0.01f;       // 1/(2*50)
  const float Sc = 2e-4f;

  // rolling per-point state (4 cols/thread)
  float cm2[4] = {0, 0, 0, 0}, cm1[4] = {0, 0, 0, 0};
  float dkA[4] = {0, 0, 0, 0}, dkB[4] = {0, 0, 0, 0};
  unsigned mAb = 0, mBb = 0;
  double accN = 0.0;
  int accD = 0;

  // clamped row windows (wave-uniform): p rows pa..pa+4, K rows ka..ka+2
  int pa = i - 2; pa = pa < 0 ? 0 : pa; pa = pa > HH - 5 ? HH - 5 : pa;
  int ka = i - 1; ka = ka < 0 ? 0 : ka; ka = ka > HH - 3 ? HH - 3 : ka;
  // rowcase: 0 interior, 1: i==0, 2: i==1, 3: i==254, 4: i==255
  const int rowcase = (i >= 2 && i <= HH - 3) ? 0
                      : (i == 0 ? 1 : (i == 1 ? 2 : (i == HH - 2 ? 3 : 4)));

  // uniform SGPR bases + 32-bit per-lane element offsets (saddr-form loads)
  const float* __restrict__ pbase = p + (size_t)b * TT * PLANE;
  const float* __restrict__ kbase = Kf + (size_t)b * TT * PLANE;
  unsigned poff = (unsigned)((pa + 2) * WW + j0);   // center p row, plane 0
  unsigned koff = (unsigned)((ka + 1) * WW + j0);   // center K row, plane 0

  F4 Ra[5], Ka[3], Rb[5], Kb[3];

#define LOADP(RR, KK) do { \
    RR[0] = *reinterpret_cast<const F4*>(pbase + poff - 2 * WW); \
    RR[1] = *reinterpret_cast<const F4*>(pbase + poff - WW); \
    RR[2] = *reinterpret_cast<const F4*>(pbase + poff); \
    RR[3] = *reinterpret_cast<const F4*>(pbase + poff + WW); \
    RR[4] = *reinterpret_cast<const F4*>(pbase + poff + 2 * WW); \
    KK[0] = *reinterpret_cast<const F4*>(kbase + koff - WW); \
    KK[1] = *reinterpret_cast<const F4*>(kbase + koff); \
    KK[2] = *reinterpret_cast<const F4*>(kbase + koff + WW); \
  } while (0)

#define BODY(RR, KK, T_) do { \
    const F4 r0v = RR[0], r1v = RR[1], r2v = RR[2], r3v = RR[3], r4v = RR[4]; \
    const F4 kAv = KK[0], kBv = KK[1], kCv = KK[2]; \
    F4 pdx4, t14, pdxx4, kdx4, kcen, pcen; \
    if (rowcase == 0) { \
      F4 gm = (r2v - r0v) * i2hx; \
      F4 gp = (r4v - r2v) * i2hx; \
      pdx4 = (r3v - r1v) * i2hx; \
      t14 = (kCv * gp - kAv * gm) * i2hx; \
      pdxx4 = (gp - gm) * i2hx; \
      kdx4 = (kCv - kAv) * i2hx; \
      kcen = kBv; pcen = r2v; \
    } else if (rowcase == 1) { \
      F4 g0 = (4.0f * r1v - 3.0f * r0v - r2v) * i2hx; \
      F4 g1 = (r2v - r0v) * i2hx; \
      F4 g2 = (r3v - r1v) * i2hx; \
      pdx4 = g0; \
      t14 = (4.0f * (kBv * g1) - 3.0f * (kAv * g0) - kCv * g2) * i2hx; \
      pdxx4 = (4.0f * g1 - 3.0f * g0 - g2) * i2hx; \
      kdx4 = (4.0f * kBv - 3.0f * kAv - kCv) * i2hx; \
      kcen = kAv; pcen = r0v; \
    } else if (rowcase == 2) { \
      F4 gm = (4.0f * r1v - 3.0f * r0v - r2v) * i2hx; \
      F4 gp = (r3v - r1v) * i2hx; \
      pdx4 = (r2v - r0v) * i2hx; \
      t14 = (kCv * gp - kAv * gm) * i2hx; \
      pdxx4 = (gp - gm) * i2hx; \
      kdx4 = (kCv - kAv) * i2hx; \
      kcen = kBv; pcen = r1v; \
    } else if (rowcase == 3) { \
      F4 gm = (r3v - r1v) * i2hx; \
      F4 gp = (3.0f * r4v - 4.0f * r3v + r2v) * i2hx; \
      pdx4 = (r4v - r2v) * i2hx; \
      t14 = (kCv * gp - kAv * gm) * i2hx; \
      pdxx4 = (gp - gm) * i2hx; \
      kdx4 = (kCv - kAv) * i2hx; \
      kcen = kBv; pcen = r3v; \
    } else { \
      F4 gm2 = (r3v - r1v) * i2hx; \
      F4 gm1 = (r4v - r2v) * i2hx; \
      F4 gN = (3.0f * r4v - 4.0f * r3v + r2v) * i2hx; \
      pdx4 = gN; \
      t14 = (3.0f * (kCv * gN) - 4.0f * (kBv * gm1) + kAv * gm2) * i2hx; \
      pdxx4 = (3.0f * gN - 4.0f * gm1 + gm2) * i2hx; \
      kdx4 = (3.0f * kCv - 4.0f * kBv + kAv) * i2hx; \
      kcen = kCv; pcen = r4v; \
    } \
    float pm2 = __shfl_up(pcen.z, 1); \
    float pm1 = __shfl_up(pcen.w, 1); \
    float pp4 = __shfl_down(pcen.x, 1); \
    float pp5 = __shfl_down(pcen.y, 1); \
    float km1 = __shfl_up(kcen.w, 1); \
    float kp4 = __shfl_down(kcen.x, 1); \
    float pcy[8] = {pm2, pm1, pcen.x, pcen.y, pcen.z, pcen.w, pp4, pp5}; \
    float kcy[6] = {km1, kcen.x, kcen.y, kcen.z, kcen.w, kp4}; \
    float pdxa[4] = {pdx4.x, pdx4.y, pdx4.z, pdx4.w}; \
    float t1a[4] = {t14.x, t14.y, t14.z, t14.w}; \
    float pdxxa[4] = {pdxx4.x, pdxx4.y, pdxx4.z, pdxx4.w}; \
    float kdxa[4] = {kdx4.x, kdx4.y, kdx4.z, kdx4.w}; \
    float divka[4]; \
    unsigned mcur = 0; \
    _Pragma("unroll") \
    for (int q = 0; q < 4; ++q) { \
      float pdy, t2, pdyy, kdy; \
      const bool edgeL = (j0 == 0) && (q <= 1); \
      const bool edgeR = (j0 == WW - 4) && (q >= 2); \
      if (!edgeL && !edgeR) { \
        float gm = (pcy[2 + q] - pcy[0 + q]) * i2hy; \
        float gp = (pcy[4 + q] - pcy[2 + q]) * i2hy; \
        pdy = (pcy[3 + q] - pcy[1 + q]) * i2hy; \
        t2 = (kcy[2 + q] * gp - kcy[q] * gm) * i2hy; \
        pdyy = (gp - gm) * i2hy; \
        kdy = (kcy[2 + q] - kcy[q]) * i2hy; \
      } else if (edgeL && q == 0) { \
        float g0 = (4.0f * pcy[3] - 3.0f * pcy[2] - pcy[4]) * i2hy; \
        float g1 = (pcy[4] - pcy[2]) * i2hy; \
        float g2 = (pcy[5] - pcy[3]) * i2hy; \
        pdy = g0; \
        t2 = (4.0f * (kcy[2] * g1) - 3.0f * (kcy[1] * g0) - kcy[3] * g2) * i2hy; \
        pdyy = (4.0f * g1 - 3.0f * g0 - g2) * i2hy; \
        kdy = (4.0f * kcy[2] - 3.0f * kcy[1] - kcy[3]) * i2hy; \
      } else if (edgeL) { \
        float gm = (4.0f * pcy[3] - 3.0f * pcy[2] - pcy[4]) * i2hy; \
        float gp = (pcy[5] - pcy[3]) * i2hy; \
        pdy = (pcy[4] - pcy[2]) * i2hy; \
        t2 = (kcy[3] * gp - kcy[1] * gm) * i2hy; \
        pdyy = (gp - gm) * i2hy; \
        kdy = (kcy[3] - kcy[1]) * i2hy; \
      } else if (q == 2) { \
        float gm = (pcy[4] - pcy[2]) * i2hy; \
        float gp = (3.0f * pcy[5] - 4.0f * pcy[4] + pcy[3]) * i2hy; \
        pdy = (pcy[5] - pcy[3]) * i2hy; \
        t2 = (kcy[4] * gp - kcy[2] * gm) * i2hy; \
        pdyy = (gp - gm) * i2hy; \
        kdy = (kcy[4] - kcy[2]) * i2hy; \
      } else { \
        float gm2 = (pcy[4] - pcy[2]) * i2hy; \
        float gm1 = (pcy[5] - pcy[3]) * i2hy; \
        float gN = (3.0f * pcy[5] - 4.0f * pcy[4] + pcy[3]) * i2hy; \
        pdy = gN; \
        t2 = (3.0f * (kcy[4] * gN) - 4.0f * (kcy[3] * gm1) + kcy[2] * gm2) * i2hy; \
        pdyy = (3.0f * gN - 4.0f * gm1 + gm2) * i2hy; \
        kdy = (3.0f * kcy[4] - 4.0f * kcy[3] + kcy[2]) * i2hy; \
      } \
      divka[q] = t1a[q] + t2; \
      float divk2 = (pdxxa[q] + pdyy) * kcy[1 + q] + pdxa[q] * kdxa[q] + pdy * kdy; \
      mcur |= (fabsf(divka[q] - divk2) < 100.0f) ? (1u << q) : 0u; \
    } \
    const bool doCompl = (T_ >= 2); \
    const bool special0 = (T_ == 2); \
    const bool edgeN = (T_ == TT - 1); \
    float cTa[4] = {pcen.x, pcen.y, pcen.z, pcen.w}; \
    float pn = 0.0f; \
    int pd = 0; \
    _Pragma("unroll") \
    for (int q = 0; q < 4; ++q) { \
      const float cT = cTa[q]; \
      if (doCompl) { \
        float pdt = (cT - cm2[q]) * 0.5f; \
        float d = dkB[q] - pdt * Sc; \
        if (mBb & (1u << q)) { pn += d * d; pd += 1; } \
        if (special0) { \
          float pdt0 = (4.0f * cm1[q] - 3.0f * cm2[q] - cT) * 0.5f; \
          float d0 = dkA[q] - pdt0 * Sc; \
          if (mAb & (1u << q)) { pn += d0 * d0; pd += 1; } \
        } \
      } \
      if (edgeN) { \
        float pdtN = (3.0f * cT - 4.0f * cm1[q] + cm2[q]) * 0.5f; \
        float dN = divka[q] - pdtN * Sc; \
        if (mcur & (1u << q)) { pn += dN * dN; pd += 1; } \
      } \
      dkA[q] = dkB[q]; dkB[q] = divka[q]; \
      cm2[q] = cm1[q]; cm1[q] = cT; \
    } \
    mAb = mBb; mBb = mcur; \
    accN += (double)pn; \
    accD += pd; \
  } while (0)

  // ---- prologue: plane 0 into buffer A ----
  LOADP(Ra, Ka);

#pragma unroll 1
  for (int t = 0; t < TT; t += 2) {
    poff += PLANE; koff += PLANE;     // plane t+1
    LOADP(Rb, Kb);                    // prefetch t+1 (t+1 <= 31 always)
    BODY(Ra, Ka, t);
    poff += PLANE; koff += PLANE;     // plane t+2
    if (t + 2 < TT) LOADP(Ra, Ka);    // prefetch t+2
    BODY(Rb, Kb, t + 1);
  }
#undef LOADP
#undef BODY

  // ---- wave + block reduction ----
  for (int off = 32; off > 0; off >>= 1) {
    accN += __shfl_down(accN, off);
    accD += __shfl_down(accD, off);
  }
  if (lane == 0) { redN[wid] = accN; redD[wid] = accD; }
  __syncthreads();
  if (tid == 0) {
    double n = 0.0; long long dd = 0;
    for (int w = 0; w < 4; ++w) { n += redN[w]; dd += redD[w]; }
    const int slot = (b << 6) + rg;    // b*64 + rg, 0..1023
    ws[slot] = n;
    ws[1024 + slot] = (double)dd;
  }
}

__global__ void pil_final(const double* __restrict__ ws, float* __restrict__ out) {
  __shared__ double s[16];
  const int tid = threadIdx.x;   // 256 threads
  const int b = tid >> 4;        // batch 0..15
  const int k = tid & 15;        // 16 threads per batch, 4 slots each
  double n = 0.0, d = 0.0;
  const int base = (b << 6) + (k << 2);
#pragma unroll
  for (int sidx = 0; sidx < 4; ++sidx) {
    n += ws[base + sidx];
    d += ws[1024 + base + sidx];
  }
  for (int off = 8; off > 0; off >>= 1) {
    n += __shfl_down(n, off, 16);
    d += __shfl_down(d, off, 16);
  }
  if (k == 0) s[b] = n / d;
  __syncthreads();
  if (tid == 0) {
    double acc = 0.0;
    for (int bb = 0; bb < 16; ++bb) acc += s[bb];
    out[0] = (float)(acc / 16.0);
  }
}

extern "C" void kernel_launch(void* const* d_in, const int* in_sizes, int n_in,
                              void* d_out, int out_size, void* d_ws, size_t ws_size,
                              hipStream_t stream) {
  const float* p = (const float*)d_in[0];
  const float* K = (const float*)d_in[1];
  double* ws = (double*)d_ws;
  float* out = (float*)d_out;
  dim3 grid(HH / 4, 16);  // (64 row-groups, 16 batches) = 1024 blocks, full T each
  pil_main<<<grid, 256, 0, stream>>>(p, K, ws);
  pil_final<<<1, 256, 0, stream>>>(ws, out);
}

// Round 7
// 74.962 us; speedup vs baseline: 1.1180x; 1.1180x over previous
//
#include <hip/hip_runtime.h>

#define HH 256
#define WW 256
#define TT 32
#define PLANE (HH * WW)
#define CHUNK 16
#define NCH 2

struct alignas(16) F4 { float x, y, z, w; };
__device__ inline F4 operator+(F4 a, F4 b) { return {a.x+b.x, a.y+b.y, a.z+b.z, a.w+b.w}; }
__device__ inline F4 operator-(F4 a, F4 b) { return {a.x-b.x, a.y-b.y, a.z-b.z, a.w-b.w}; }
__device__ inline F4 operator*(F4 a, F4 b) { return {a.x*b.x, a.y*b.y, a.z*b.z, a.w*b.w}; }
__device__ inline F4 operator*(F4 a, float s) { return {a.x*s, a.y*s, a.z*s, a.w*s}; }
__device__ inline F4 operator*(float s, F4 a) { return {a.x*s, a.y*s, a.z*s, a.w*s}; }

// y-direction stencil + divk/divk2/mask for one row.
// Inputs: PC (center p F4), KC (center K F4), PDX,T1,PDXX,KDX (x-terms).
// Outputs: DIVKA[4], MCUR.
#define YDIVK(PC, KC, PDX, T1, PDXX, KDX, DIVKA, MCUR) do { \
    float pm2 = __shfl_up(PC.z, 1); \
    float pm1 = __shfl_up(PC.w, 1); \
    float pp4 = __shfl_down(PC.x, 1); \
    float pp5 = __shfl_down(PC.y, 1); \
    float km1 = __shfl_up(KC.w, 1); \
    float kp4 = __shfl_down(KC.x, 1); \
    float pcy[8] = {pm2, pm1, PC.x, PC.y, PC.z, PC.w, pp4, pp5}; \
    float kcy[6] = {km1, KC.x, KC.y, KC.z, KC.w, kp4}; \
    float pdxa[4] = {PDX.x, PDX.y, PDX.z, PDX.w}; \
    float t1a[4] = {T1.x, T1.y, T1.z, T1.w}; \
    float pdxxa[4] = {PDXX.x, PDXX.y, PDXX.z, PDXX.w}; \
    float kdxa[4] = {KDX.x, KDX.y, KDX.z, KDX.w}; \
    _Pragma("unroll") \
    for (int q = 0; q < 4; ++q) { \
      float pdy, t2, pdyy, kdy; \
      const bool edgeL = (j0 == 0) && (q <= 1); \
      const bool edgeR = (j0 == WW - 4) && (q >= 2); \
      if (!edgeL && !edgeR) { \
        float gm = (pcy[2 + q] - pcy[0 + q]) * i2hy; \
        float gp = (pcy[4 + q] - pcy[2 + q]) * i2hy; \
        pdy = (pcy[3 + q] - pcy[1 + q]) * i2hy; \
        t2 = (kcy[2 + q] * gp - kcy[q] * gm) * i2hy; \
        pdyy = (gp - gm) * i2hy; \
        kdy = (kcy[2 + q] - kcy[q]) * i2hy; \
      } else if (edgeL && q == 0) { \
        float g0 = (4.0f * pcy[3] - 3.0f * pcy[2] - pcy[4]) * i2hy; \
        float g1 = (pcy[4] - pcy[2]) * i2hy; \
        float g2 = (pcy[5] - pcy[3]) * i2hy; \
        pdy = g0; \
        t2 = (4.0f * (kcy[2] * g1) - 3.0f * (kcy[1] * g0) - kcy[3] * g2) * i2hy; \
        pdyy = (4.0f * g1 - 3.0f * g0 - g2) * i2hy; \
        kdy = (4.0f * kcy[2] - 3.0f * kcy[1] - kcy[3]) * i2hy; \
      } else if (edgeL) { \
        float gm = (4.0f * pcy[3] - 3.0f * pcy[2] - pcy[4]) * i2hy; \
        float gp = (pcy[5] - pcy[3]) * i2hy; \
        pdy = (pcy[4] - pcy[2]) * i2hy; \
        t2 = (kcy[3] * gp - kcy[1] * gm) * i2hy; \
        pdyy = (gp - gm) * i2hy; \
        kdy = (kcy[3] - kcy[1]) * i2hy; \
      } else if (q == 2) { \
        float gm = (pcy[4] - pcy[2]) * i2hy; \
        float gp = (3.0f * pcy[5] - 4.0f * pcy[4] + pcy[3]) * i2hy; \
        pdy = (pcy[5] - pcy[3]) * i2hy; \
        t2 = (kcy[4] * gp - kcy[2] * gm) * i2hy; \
        pdyy = (gp - gm) * i2hy; \
        kdy = (kcy[4] - kcy[2]) * i2hy; \
      } else { \
        float gm2 = (pcy[4] - pcy[2]) * i2hy; \
        float gm1 = (pcy[5] - pcy[3]) * i2hy; \
        float gN = (3.0f * pcy[5] - 4.0f * pcy[4] + pcy[3]) * i2hy; \
        pdy = gN; \
        t2 = (3.0f * (kcy[4] * gN) - 4.0f * (kcy[3] * gm1) + kcy[2] * gm2) * i2hy; \
        pdyy = (3.0f * gN - 4.0f * gm1 + gm2) * i2hy; \
        kdy = (3.0f * kcy[4] - 4.0f * kcy[3] + kcy[2]) * i2hy; \
      } \
      DIVKA[q] = t1a[q] + t2; \
      float divk2 = (pdxxa[q] + pdyy) * kcy[1 + q] + pdxa[q] * kdxa[q] + pdy * kdy; \
      MCUR |= (fabsf(DIVKA[q] - divk2) < 100.0f) ? (1u << q) : 0u; \
    } \
  } while (0)

// loss contributions + rolling-state update for one row.
#define ROLL(PC, CM2, CM1, DKA, DKB, MAB, MBB, DIVKA, MCUR) do { \
    float cTa[4] = {PC.x, PC.y, PC.z, PC.w}; \
    _Pragma("unroll") \
    for (int q = 0; q < 4; ++q) { \
      const float cT = cTa[q]; \
      if (doCompl) { \
        float pdt = (cT - CM2[q]) * 0.5f; \
        float d = DKB[q] - pdt * Sc; \
        if (MBB & (1u << q)) { pn += d * d; pd += 1; } \
        if (special0) { \
          float pdt0 = (4.0f * CM1[q] - 3.0f * CM2[q] - cT) * 0.5f; \
          float d0 = DKA[q] - pdt0 * Sc; \
          if (MAB & (1u << q)) { pn += d0 * d0; pd += 1; } \
        } \
      } \
      if (edgeN) { \
        float pdtN = (3.0f * cT - 4.0f * CM1[q] + CM2[q]) * 0.5f; \
        float dN = DIVKA[q] - pdtN * Sc; \
        if (MCUR & (1u << q)) { pn += dN * dN; pd += 1; } \
      } \
      DKA[q] = DKB[q]; DKB[q] = DIVKA[q]; \
      CM2[q] = CM1[q]; CM1[q] = cT; \
    } \
    MAB = MBB; MBB = MCUR; \
  } while (0)

__global__ __launch_bounds__(256) void pil_main(const float* __restrict__ p,
                                                const float* __restrict__ Kf,
                                                double* __restrict__ ws) {
  __shared__ double redN[4];
  __shared__ int redD[4];

  const int rg = blockIdx.x;      // 0..31, 8 rows per block
  const int b = blockIdx.y;       // 0..15
  const int c = blockIdx.z;       // 0..1
  const int t0 = c * CHUNK;
  const bool hasPre = (c != 0);
  const bool hasPost = (c != NCH - 1);

  const int tid = threadIdx.x;
  const int wid = tid >> 6;
  const int lane = tid & 63;
  const int iA = (rg << 3) + (wid << 1);   // even row of the pair (wave-uniform)
  const int j0 = lane << 2;

  const float i2hx = 0.02f;       // 1/(2*25)
  const float i2hy = 0.01f;       // 1/(2*50)
  const float Sc = 2e-4f;

  // wave class: 0 interior, 1 rows {0,1}, 2 rows {254,255}
  const int wc = (iA == 0) ? 1 : ((iA == HH - 2) ? 2 : 0);

  // clamped windows: p rows pa..pa+5, K rows ka..ka+3 (wave-uniform)
  int pa = iA - 2; pa = pa < 0 ? 0 : pa; pa = pa > HH - 6 ? HH - 6 : pa;
  int ka = iA - 1; ka = ka < 0 ? 0 : ka; ka = ka > HH - 4 ? HH - 4 : ka;

  const float* __restrict__ pbase = p + (size_t)b * TT * PLANE;
  const float* __restrict__ kbase = Kf + (size_t)b * TT * PLANE;
  unsigned poff = (unsigned)(t0 * PLANE + pa * WW + j0);
  unsigned koff = (unsigned)(t0 * PLANE + ka * WW + j0);
  const unsigned crowA = (unsigned)(iA * WW + j0);

  // rolling state, per row
  float cm2A[4] = {0,0,0,0}, cm1A[4] = {0,0,0,0}, dkAA[4] = {0,0,0,0}, dkBA[4] = {0,0,0,0};
  float cm2B[4] = {0,0,0,0}, cm1B[4] = {0,0,0,0}, dkAB[4] = {0,0,0,0}, dkBB[4] = {0,0,0,0};
  unsigned mAbA = 0, mBbA = 0, mAbB = 0, mBbB = 0;
  double accN = 0.0;
  int accD = 0;

  if (hasPre) {  // plane t0-1 center rows seed cm1
    F4 hA = *reinterpret_cast<const F4*>(pbase + (size_t)(t0 - 1) * PLANE + crowA);
    F4 hB = *reinterpret_cast<const F4*>(pbase + (size_t)(t0 - 1) * PLANE + crowA + WW);
    cm1A[0] = hA.x; cm1A[1] = hA.y; cm1A[2] = hA.z; cm1A[3] = hA.w;
    cm1B[0] = hB.x; cm1B[1] = hB.y; cm1B[2] = hB.z; cm1B[3] = hB.w;
  }

#pragma unroll 1
  for (int s = 0; s < CHUNK; ++s) {
    // ---- 10 coalesced loads: 6 p rows + 4 K rows cover BOTH output rows ----
    F4 P0 = *reinterpret_cast<const F4*>(pbase + poff);
    F4 P1 = *reinterpret_cast<const F4*>(pbase + poff + WW);
    F4 P2 = *reinterpret_cast<const F4*>(pbase + poff + 2 * WW);
    F4 P3 = *reinterpret_cast<const F4*>(pbase + poff + 3 * WW);
    F4 P4 = *reinterpret_cast<const F4*>(pbase + poff + 4 * WW);
    F4 P5 = *reinterpret_cast<const F4*>(pbase + poff + 5 * WW);
    F4 K0 = *reinterpret_cast<const F4*>(kbase + koff);
    F4 K1 = *reinterpret_cast<const F4*>(kbase + koff + WW);
    F4 K2 = *reinterpret_cast<const F4*>(kbase + koff + 2 * WW);
    F4 K3 = *reinterpret_cast<const F4*>(kbase + koff + 3 * WW);
    poff += PLANE; koff += PLANE;

    // ---- x-direction terms for both rows (wave-uniform branch) ----
    F4 pdxA, t1A, pdxxA, kdxA, kcA, pcA;
    F4 pdxB, t1B, pdxxB, kdxB, kcB, pcB;
    if (wc == 0) {  // interior: shared gradients g(iA-1),g(iA),g(iA+1),g(iA+2)
      F4 g0 = (P2 - P0) * i2hx;   // g(iA-1)
      F4 g1 = (P3 - P1) * i2hx;   // g(iA)
      F4 g2 = (P4 - P2) * i2hx;   // g(iA+1)
      F4 g3 = (P5 - P3) * i2hx;   // g(iA+2)
      pdxA = g1;
      t1A = (K2 * g2 - K0 * g0) * i2hx;
      pdxxA = (g2 - g0) * i2hx;
      kdxA = (K2 - K0) * i2hx;
      kcA = K1; pcA = P2;
      pdxB = g2;
      t1B = (K3 * g3 - K1 * g1) * i2hx;
      pdxxB = (g3 - g1) * i2hx;
      kdxB = (K3 - K1) * i2hx;
      kcB = K2; pcB = P3;
    } else if (wc == 1) {  // rows 0,1 (pa=0, ka=0; P0..P3 = rows 0..3)
      F4 g0 = (4.0f * P1 - 3.0f * P0 - P2) * i2hx;  // g(0) edge
      F4 g1 = (P2 - P0) * i2hx;                      // g(1)
      F4 g2 = (P3 - P1) * i2hx;                      // g(2)
      pdxA = g0;
      t1A = (4.0f * (K1 * g1) - 3.0f * (K0 * g0) - K2 * g2) * i2hx;
      pdxxA = (4.0f * g1 - 3.0f * g0 - g2) * i2hx;
      kdxA = (4.0f * K1 - 3.0f * K0 - K2) * i2hx;
      kcA = K0; pcA = P0;
      pdxB = g1;
      t1B = (K2 * g2 - K0 * g0) * i2hx;
      pdxxB = (g2 - g0) * i2hx;
      kdxB = (K2 - K0) * i2hx;
      kcB = K1; pcB = P1;
    } else {  // rows 254,255 (pa=250, ka=252; P2..P5 = rows 252..255, K1..K3 = 253..255)
      F4 gm2 = (P4 - P2) * i2hx;                      // g(253)
      F4 gm1 = (P5 - P3) * i2hx;                      // g(254)
      F4 gN = (3.0f * P5 - 4.0f * P4 + P3) * i2hx;    // g(255) edge
      pdxA = gm1;
      t1A = (K3 * gN - K1 * gm2) * i2hx;
      pdxxA = (gN - gm2) * i2hx;
      kdxA = (K3 - K1) * i2hx;
      kcA = K2; pcA = P4;
      pdxB = gN;
      t1B = (3.0f * (K3 * gN) - 4.0f * (K2 * gm1) + K1 * gm2) * i2hx;
      pdxxB = (3.0f * gN - 4.0f * gm1 + gm2) * i2hx;
      kdxB = (3.0f * K3 - 4.0f * K2 + K1) * i2hx;
      kcB = K3; pcB = P5;
    }

    // ---- y-direction + divk + mask, per row ----
    float divkaA[4]; unsigned mcurA = 0;
    YDIVK(pcA, kcA, pdxA, t1A, pdxxA, kdxA, divkaA, mcurA);
    float divkaB[4]; unsigned mcurB = 0;
    YDIVK(pcB, kcB, pdxB, t1B, pdxxB, kdxB, divkaB, mcurB);

    // ---- deferred p_dt completion + state roll ----
    const bool doCompl = (s >= ((c == 0) ? 2 : 1));
    const bool special0 = (c == 0) && (s == 2);
    const bool edgeN = (c == NCH - 1) && (s == CHUNK - 1);
    float pn = 0.0f;
    int pd = 0;
    ROLL(pcA, cm2A, cm1A, dkAA, dkBA, mAbA, mBbA, divkaA, mcurA);
    ROLL(pcB, cm2B, cm1B, dkAB, dkBB, mAbB, mBbB, divkaB, mcurB);
    accN += (double)pn;
    accD += pd;
  }

  if (hasPost) {  // plane t0+CHUNK center rows complete plane t0+CHUNK-1
    F4 hA = *reinterpret_cast<const F4*>(pbase + (size_t)(t0 + CHUNK) * PLANE + crowA);
    F4 hB = *reinterpret_cast<const F4*>(pbase + (size_t)(t0 + CHUNK) * PLANE + crowA + WW);
    float cPa[4] = {hA.x, hA.y, hA.z, hA.w};
    float cPb[4] = {hB.x, hB.y, hB.z, hB.w};
    float pn = 0.0f;
    int pd = 0;
#pragma unroll
    for (int q = 0; q < 4; ++q) {
      float pdtA = (cPa[q] - cm2A[q]) * 0.5f;
      float dA = dkBA[q] - pdtA * Sc;
      if (mBbA & (1u << q)) { pn += dA * dA; pd += 1; }
      float pdtB = (cPb[q] - cm2B[q]) * 0.5f;
      float dB = dkBB[q] - pdtB * Sc;
      if (mBbB & (1u << q)) { pn += dB * dB; pd += 1; }
    }
    accN += (double)pn;
    accD += pd;
  }

  // ---- wave + block reduction ----
  for (int off = 32; off > 0; off >>= 1) {
    accN += __shfl_down(accN, off);
    accD += __shfl_down(accD, off);
  }
  if (lane == 0) { redN[wid] = accN; redD[wid] = accD; }
  __syncthreads();
  if (tid == 0) {
    double n = 0.0; long long dd = 0;
    for (int w = 0; w < 4; ++w) { n += redN[w]; dd += redD[w]; }
    const int slot = ((b << 5) + rg) * 2 + c;   // b*64 + rg*2 + c, 0..1023
    ws[slot] = n;
    ws[1024 + slot] = (double)dd;
  }
}

__global__ void pil_final(const double* __restrict__ ws, float* __restrict__ out) {
  __shared__ double s[16];
  const int tid = threadIdx.x;   // 256 threads
  const int b = tid >> 4;        // batch 0..15
  const int k = tid & 15;        // 16 threads per batch, 4 slots each
  double n = 0.0, d = 0.0;
  const int base = (b << 6) + (k << 2);
#pragma unroll
  for (int sidx = 0; sidx < 4; ++sidx) {
    n += ws[base + sidx];
    d += ws[1024 + base + sidx];
  }
  for (int off = 8; off > 0; off >>= 1) {
    n += __shfl_down(n, off, 16);
    d += __shfl_down(d, off, 16);
  }
  if (k == 0) s[b] = n / d;
  __syncthreads();
  if (tid == 0) {
    double acc = 0.0;
    for (int bb = 0; bb < 16; ++bb) acc += s[bb];
    out[0] = (float)(acc / 16.0);
  }
}

extern "C" void kernel_launch(void* const* d_in, const int* in_sizes, int n_in,
                              void* d_out, int out_size, void* d_ws, size_t ws_size,
                              hipStream_t stream) {
  const float* p = (const float*)d_in[0];
  const float* K = (const float*)d_in[1];
  double* ws = (double*)d_ws;
  float* out = (float*)d_out;
  dim3 grid(HH / 8, 16, NCH);  // (32 row-groups of 8 rows, 16 batches, 2 chunks) = 1024 blocks
  pil_main<<<grid, 256, 0, stream>>>(p, K, ws);
  pil_final<<<1, 256, 0, stream>>>(ws, out);
}